// Round 4
// baseline (718.271 us; speedup 1.0000x reference)
//
#include <hip/hip_runtime.h>

// ---------------------------------------------------------------------------
// ContrastiveLoss (SCAN t2i cross-attention) on MI355X — round 4.
// N=256x256 pairs, R=36 regions, L=50 words, D=256.
// Barrier-free xattn: each wave owns one (i,j) pair end-to-end.
//   G[r,l] = <im_i[r], s_j[l]>            (bf16 MFMA, f32 accum)
//   rinv[r]= 9*log2e/(||leaky(G[r,:len])||+eps)
//   p[r,l] = exp2(leaky(G)*rinv)          (max-free: |arg| <= 13)
//   num[l] = sum_r p*G   (inline); t = Gram_i @ p (bf16 MFMA)
//   wn2[l] = sum_r p*t   (fragment elementwise + shfl)
//   score  = log2(sum_l exp2(6*log2e*sim))*ln2/6   (max-free: |arg| <= ~9)
// ---------------------------------------------------------------------------

typedef unsigned short u16;
typedef unsigned int u32;

typedef __attribute__((ext_vector_type(8))) __bf16 bf16x8;
typedef __attribute__((ext_vector_type(4))) float floatx4;

#define NN 256
#define RR 36
#define LL 50
#define DD 256
#define RP 48    // padded region dim
#define LP 64    // padded word dim (s rows)
#define KP 64    // gram row stride / matvec K
#define ASTR 68  // u16 stride of LDS rows
#define WROWS 50 // logical LDS rows per wave
#define SLOP 14  // shared overflow rows (reads of rows 50..63 land here)

__device__ __forceinline__ u16 f2bf(float v) {
  u32 u = __builtin_bit_cast(u32, v);
  u += 0x7fffu + ((u >> 16) & 1u);   // RNE (inputs never NaN)
  return (u16)(u >> 16);
}
__device__ __forceinline__ float bflo(u32 w) { return __builtin_bit_cast(float, w << 16); }
__device__ __forceinline__ float bfhi(u32 w) { return __builtin_bit_cast(float, w & 0xffff0000u); }

#define WAVE_SYNC() do { \
  asm volatile("s_waitcnt lgkmcnt(0)" ::: "memory"); \
  __builtin_amdgcn_sched_barrier(0); \
} while (0)

// ---- prep: im -> bf16 padded [48][256] ------------------------------------
__global__ void prep_im_kernel(const float* __restrict__ im,
                               u16* __restrict__ im_bf) {
  const int i = blockIdx.x;
  const int t = threadIdx.x;
  const float* src = im + (size_t)i * (RR * DD);
  u16* dst = im_bf + (size_t)i * (RP * DD);
  for (int e = t; e < RR * DD; e += 256) dst[e] = f2bf(src[e]);
  for (int e = RR * DD + t; e < RP * DD; e += 256) dst[e] = 0;
}

// ---- prep: Gram_i = im_i im_i^T via MFMA -> bf16 [48][64] -----------------
__global__ __launch_bounds__(64) void prep_gram_kernel(const u16* __restrict__ im_bf,
                                                       u16* __restrict__ gram_bf) {
  const int i = blockIdx.x;
  const int lane = threadIdx.x;
  const int lo = lane & 15, hi = lane >> 4;
  floatx4 acc[3][3];
  #pragma unroll
  for (int m = 0; m < 3; ++m)
    #pragma unroll
    for (int n = 0; n < 3; ++n) acc[m][n] = floatx4{0.f, 0.f, 0.f, 0.f};
  const u16* imp = im_bf + (size_t)i * (RP * DD);
  #pragma unroll 2
  for (int kt = 0; kt < 8; ++kt) {
    const int k0 = (kt << 5) + (hi << 3);
    bf16x8 f[3];
    #pragma unroll
    for (int m = 0; m < 3; ++m)
      f[m] = __builtin_bit_cast(bf16x8, *(const uint4*)(imp + (m * 16 + lo) * DD + k0));
    #pragma unroll
    for (int m = 0; m < 3; ++m)
      #pragma unroll
      for (int n = 0; n < 3; ++n)
        acc[m][n] = __builtin_amdgcn_mfma_f32_16x16x32_bf16(f[m], f[n], acc[m][n], 0, 0, 0);
  }
  u16* g = gram_bf + (size_t)i * (RP * KP);
  #pragma unroll
  for (int m = 0; m < 3; ++m)
    #pragma unroll
    for (int n = 0; n < 3; ++n)
      #pragma unroll
      for (int q = 0; q < 4; ++q)
        g[(m * 16 + hi * 4 + q) * KP + n * 16 + lo] = f2bf(acc[m][n][q]);
  // zero cols 48..63 (rows 36..47 are zero automatically via padded im rows)
  for (int e = lane; e < RP * 16; e += 64) {
    int r = e >> 4, c = e & 15;
    g[r * KP + 48 + c] = 0;
  }
}

// ---- prep: s -> bf16 padded [64][256], cn[j,l] = ||s_j[l]|| ---------------
__global__ void prep_s_kernel(const float* __restrict__ s,
                              u16* __restrict__ s_bf,
                              float* __restrict__ cn) {
  const int j = blockIdx.x;
  const int t = threadIdx.x;
  const float* src = s + (size_t)j * (LL * DD);
  u16* dst = s_bf + (size_t)j * (LP * DD);
  for (int e = t; e < LL * DD; e += 256) dst[e] = f2bf(src[e]);
  for (int e = LL * DD + t; e < LP * DD; e += 256) dst[e] = 0;
  const int l = t >> 2, q = t & 3;
  float acc = 0.f;
  if (l < LL) {
    const float* row = src + l * DD + q * 64;
    #pragma unroll 4
    for (int d = 0; d < 64; ++d) { float v = row[d]; acc = fmaf(v, v, acc); }
  }
  acc += __shfl_xor(acc, 1);
  acc += __shfl_xor(acc, 2);
  if (l < LL && q == 0) cn[j * LL + l] = sqrtf(acc);
}

// ---- main: 4 independent waves/block, one (i,j) pair per wave -------------
__global__ __launch_bounds__(256, 5) void xattn_kernel(
    const u16* __restrict__ im_bf, const u16* __restrict__ s_bf,
    const u16* __restrict__ gram_bf, const float* __restrict__ cn,
    const int* __restrict__ cap, float* __restrict__ scores) {
  __shared__ u16 buf[(4 * WROWS + SLOP) * ASTR];  // 29,104 B

  const int wid  = threadIdx.x >> 6;
  const int lane = threadIdx.x & 63;
  const int lo = lane & 15, hi = lane >> 4;
  const int i = blockIdx.x >> 6;
  const int j = ((blockIdx.x & 63) << 2) | wid;
  const int len = cap[j];
  const int nv = (len > 48) ? 4 : 3;  // wave-uniform n-tile count

  u16* mybuf = buf + wid * (WROWS * ASTR);

  // ---- Phase A: G = im_i @ s_j^T (M=48, N=16*nv, K=256) -------------------
  floatx4 acc[3][4];
  #pragma unroll
  for (int m = 0; m < 3; ++m)
    #pragma unroll
    for (int n = 0; n < 4; ++n) acc[m][n] = floatx4{0.f, 0.f, 0.f, 0.f};

  const u16* imp = im_bf + (size_t)i * (RP * DD);
  const u16* sp  = s_bf  + (size_t)j * (LP * DD);

  #pragma unroll 2
  for (int kt = 0; kt < 8; ++kt) {
    const int k0 = (kt << 5) + (hi << 3);
    bf16x8 af[3], bfr[4];
    #pragma unroll
    for (int m = 0; m < 3; ++m)
      af[m] = __builtin_bit_cast(bf16x8, *(const uint4*)(imp + (m * 16 + lo) * DD + k0));
    #pragma unroll
    for (int n = 0; n < 4; ++n)
      if (n < nv)
        bfr[n] = __builtin_bit_cast(bf16x8, *(const uint4*)(sp + (n * 16 + lo) * DD + k0));
    #pragma unroll
    for (int m = 0; m < 3; ++m)
      #pragma unroll
      for (int n = 0; n < 4; ++n)
        if (n < nv)
          acc[m][n] = __builtin_amdgcn_mfma_f32_16x16x32_bf16(af[m], bfr[n], acc[m][n], 0, 0, 0);
  }

  // Gram A-fragments (issued early; consumed in matvec — latency hidden)
  bf16x8 gA[3][2];
  const u16* gp = gram_bf + (size_t)i * (RP * KP);
  #pragma unroll
  for (int m = 0; m < 3; ++m)
    #pragma unroll
    for (int kt = 0; kt < 2; ++kt)
      gA[m][kt] = __builtin_bit_cast(bf16x8,
          *(const uint4*)(gp + (m * 16 + lo) * KP + (kt << 5) + (hi << 3)));

  // write G^T to LDS bf16: buf[l][r]; row = 16n+lo, only rows < 50 owned
  #pragma unroll
  for (int n = 0; n < 4; ++n) {
    if (n < nv && (n < 3 || lo < 2)) {
      #pragma unroll
      for (int m = 0; m < 3; ++m) {
        u32 w0 = (u32)f2bf(acc[m][n][0]) | ((u32)f2bf(acc[m][n][1]) << 16);
        u32 w1 = (u32)f2bf(acc[m][n][2]) | ((u32)f2bf(acc[m][n][3]) << 16);
        uint2 t; t.x = w0; t.y = w1;
        *(uint2*)&mybuf[(n * 16 + lo) * ASTR + m * 16 + hi * 4] = t;
      }
    }
  }
  // zero cols 48..63 of own row (K-pad for matvec kt=1)
  if (lane < WROWS) {
    uint2 z2 = {0u, 0u};
    uint2* zp = (uint2*)&mybuf[lane * ASTR + 48];
    zp[0] = z2; zp[1] = z2; zp[2] = z2; zp[3] = z2;
  }
  WAVE_SYNC();

  // ---- C1: per-region row norms over valid words --------------------------
  float rinv = 0.f;
  if (lane < RR) {
    float ss = 0.f;
    for (int l = 0; l < len; ++l) {
      float g = bflo((u32)mybuf[l * ASTR + lane]);
      float v = fmaxf(g, 0.1f * g);
      ss = fmaf(v, v, ss);
    }
    rinv = 12.984255368000671f / (sqrtf(ss) + 1e-8f);  // 9*log2e/(norm+eps)
  }
  float sr[RR];
  #pragma unroll
  for (int r = 0; r < RR; ++r)
    sr[r] = __builtin_bit_cast(float,
        __builtin_amdgcn_readlane(__builtin_bit_cast(int, rinv), r));

  // ---- C2: single-pass max-free softmax (lane = word l), a^T in place -----
  u32 rw[18];
  {
    const uint2* rp = (const uint2*)&mybuf[lane * ASTR];
    #pragma unroll
    for (int k = 0; k < 9; ++k) { uint2 t = rp[k]; rw[2 * k] = t.x; rw[2 * k + 1] = t.y; }
  }
  float psum = 0.f, num = 0.f, pe = 0.f;
  u32 pk[18];
  #pragma unroll
  for (int r = 0; r < RR; ++r) {
    u32 w = rw[r >> 1];
    float g = (r & 1) ? bfhi(w) : bflo(w);
    float v = fmaxf(g, 0.1f * g) * sr[r];   // bounded: |v| <= 9*log2e
    float p = exp2f(v);
    psum += p;
    num = fmaf(p, g, num);
    if (r & 1) pk[r >> 1] = (u32)f2bf(pe) | ((u32)f2bf(p) << 16);
    else pe = p;
  }
  if (lane < WROWS) {  // own row only (lanes 50..63 would corrupt neighbor)
    uint2* wp = (uint2*)&mybuf[lane * ASTR];
    #pragma unroll
    for (int k = 0; k < 9; ++k) { uint2 t; t.x = pk[2 * k]; t.y = pk[2 * k + 1]; wp[k] = t; }
  }
  WAVE_SYNC();

  // ---- matvec: t = Gram_i @ p  (M=48, N=16*nv, K=64 zero-padded) ----------
  floatx4 tac[3][4];
  #pragma unroll
  for (int m = 0; m < 3; ++m)
    #pragma unroll
    for (int n = 0; n < 4; ++n) tac[m][n] = floatx4{0.f, 0.f, 0.f, 0.f};

  #pragma unroll
  for (int kt = 0; kt < 2; ++kt) {
    bf16x8 gB[4];
    #pragma unroll
    for (int n = 0; n < 4; ++n) {
      if (n < nv) {
        const uint2* bp = (const uint2*)&mybuf[(n * 16 + lo) * ASTR + (kt << 5) + (hi << 3)];
        uint2 b0 = bp[0], b1 = bp[1];
        uint4 bb; bb.x = b0.x; bb.y = b0.y; bb.z = b1.x; bb.w = b1.y;
        gB[n] = __builtin_bit_cast(bf16x8, bb);
      }
    }
    #pragma unroll
    for (int m = 0; m < 3; ++m)
      #pragma unroll
      for (int n = 0; n < 4; ++n)
        if (n < nv)
          tac[m][n] = __builtin_amdgcn_mfma_f32_16x16x32_bf16(gA[m][kt], gB[n], tac[m][n], 0, 0, 0);
  }

  // ---- wn2 = sum_r p*t per column + finalize + max-free LSE ---------------
  float e4 = 0.f;
  #pragma unroll
  for (int n = 0; n < 4; ++n) {
    if (n < nv) {
      float w = 0.f;
      #pragma unroll
      for (int m = 0; m < 3; ++m) {
        uint2 av = *(const uint2*)&mybuf[(n * 16 + lo) * ASTR + m * 16 + hi * 4];
        w = fmaf(bflo(av.x), tac[m][n][0], w);
        w = fmaf(bfhi(av.x), tac[m][n][1], w);
        w = fmaf(bflo(av.y), tac[m][n][2], w);
        w = fmaf(bfhi(av.y), tac[m][n][3], w);
      }
      w += __shfl_xor(w, 16);
      w += __shfl_xor(w, 32);     // all hi-duplicates hold full sum over r
      const int col = n * 16 + lo;
      float numc = __shfl(num, col);
      float psc  = __shfl(psum, col);
      if (col < len) {
        float inv = __builtin_amdgcn_rcpf(psc);
        float wn2 = fmaxf(w * inv * inv, 0.f);
        float nm  = numc * inv;
        float den = fmaxf(sqrtf(wn2) * cn[j * LL + col], 1e-8f);
        float sim = nm * __builtin_amdgcn_rcpf(den);
        e4 += exp2f(sim * 8.656170245333781f);   // 6*log2e; |arg| ~<= 9
      }
    }
  }
  #pragma unroll
  for (int off = 1; off < 64; off <<= 1) e4 += __shfl_xor(e4, off);
  if (lane == 0)
    scores[i * NN + j] = (log2f(e4) - 2.0f) * 0.11552453009332421f; // ln2/6
}

// ---- loss: hinge terms vs diagonal, full reduction ------------------------
__global__ void loss_kernel(const float* __restrict__ sc, float* __restrict__ out) {
  __shared__ float diag[NN];
  __shared__ float wsum[4];
  const int t = threadIdx.x;
  diag[t] = sc[t * NN + t];
  __syncthreads();
  const float di = diag[t];
  const float4* row = (const float4*)(sc + t * NN);
  float acc = 0.f;
  for (int q = 0; q < 64; ++q) {
    float4 v = row[q];
    const int b = q * 4;
    if (b + 0 != t) acc += fmaxf(0.2f + v.x - di, 0.f) + fmaxf(0.2f + v.x - diag[b + 0], 0.f);
    if (b + 1 != t) acc += fmaxf(0.2f + v.y - di, 0.f) + fmaxf(0.2f + v.y - diag[b + 1], 0.f);
    if (b + 2 != t) acc += fmaxf(0.2f + v.z - di, 0.f) + fmaxf(0.2f + v.z - diag[b + 2], 0.f);
    if (b + 3 != t) acc += fmaxf(0.2f + v.w - di, 0.f) + fmaxf(0.2f + v.w - diag[b + 3], 0.f);
  }
  #pragma unroll
  for (int o = 32; o; o >>= 1) acc += __shfl_xor(acc, o);
  if ((t & 63) == 0) wsum[t >> 6] = acc;
  __syncthreads();
  if (t == 0) out[0] = wsum[0] + wsum[1] + wsum[2] + wsum[3];
}

// ---------------------------------------------------------------------------
extern "C" void kernel_launch(void* const* d_in, const int* in_sizes, int n_in,
                              void* d_out, int out_size, void* d_ws, size_t ws_size,
                              hipStream_t stream) {
  const float* im = (const float*)d_in[0];
  const float* s  = (const float*)d_in[1];
  const int* cap  = (const int*)d_in[2];
  float* out = (float*)d_out;

  char* ws = (char*)d_ws;
  u16*   im_bf   = (u16*)(ws);                         //  6,291,456 B
  u16*   s_bf    = (u16*)(ws + 6291456);               //  8,388,608 B
  u16*   gram_bf = (u16*)(ws + 14680064);              //  1,572,864 B
  float* cn      = (float*)(ws + 16252928);            //     51,200 B
  float* scores  = (float*)(ws + 16304128);            //    262,144 B

  prep_im_kernel<<<dim3(NN), dim3(256), 0, stream>>>(im, im_bf);
  prep_s_kernel<<<dim3(NN), dim3(256), 0, stream>>>(s, s_bf, cn);
  prep_gram_kernel<<<dim3(NN), dim3(64), 0, stream>>>(im_bf, gram_bf);
  xattn_kernel<<<dim3(NN * 64), dim3(256), 0, stream>>>(im_bf, s_bf, gram_bf, cn, cap, scores);
  loss_kernel<<<dim3(1), dim3(256), 0, stream>>>(scores, out);
}

// Round 5
// 564.844 us; speedup vs baseline: 1.2716x; 1.2716x over previous
//
#include <hip/hip_runtime.h>

// ---------------------------------------------------------------------------
// ContrastiveLoss (SCAN t2i cross-attention) on MI355X — round 5.
// N=256x256 pairs, R=36 regions, L=50 words, D=256.
// Barrier-free xattn; softmax/norms computed IN the MFMA fragments:
//   G[r,l] = <im_i[r], s_j[l]>          (bf16 MFMA, f32 accum; D-frag regs)
//   ss[r]  = sum_{l<len} leaky(G)^2      (frag partials + shfl_xor over lo)
//   p[r,l] = exp2(leaky(G)*9*log2e/(sqrt(ss)+eps))   (max-free, |arg|<=13)
//   num[l] = sum_r p*G ; psum[l] = sum_r p  (frag partials + shfl_xor over hi)
//   t = Gram_i @ p (bf16 MFMA; p via LDS [l][r]); wn2[l] = sum_r p*t
//   score = log2(sum_l exp2(6*log2e*sim))*ln2/6  (max-free, 4x-dup => -2)
// ---------------------------------------------------------------------------

typedef unsigned short u16;
typedef unsigned int u32;

typedef __attribute__((ext_vector_type(8))) __bf16 bf16x8;
typedef __attribute__((ext_vector_type(4))) __bf16 bf16x4;
typedef __attribute__((ext_vector_type(4))) float floatx4;

#define NN 256
#define RR 36
#define LL 50
#define DD 256
#define RP 48    // padded region dim
#define LP 64    // padded word dim (s rows)
#define KP 64    // gram row stride / matvec K
#define ASTR 68  // u16 stride of LDS rows (136B: lo-lanes spread all banks)
#define WROWS 50 // logical LDS rows per wave
#define SLOP 14  // shared overflow rows (reads of rows 50..63 land here)

__device__ __forceinline__ u16 f2bf(float v) {
  u32 u = __builtin_bit_cast(u32, v);
  u += 0x7fffu + ((u >> 16) & 1u);   // RNE (inputs never NaN)
  return (u16)(u >> 16);
}
__device__ __forceinline__ float bflo(u32 w) { return __builtin_bit_cast(float, w << 16); }
__device__ __forceinline__ float bfhi(u32 w) { return __builtin_bit_cast(float, w & 0xffff0000u); }

#define WAVE_SYNC() do { \
  asm volatile("s_waitcnt lgkmcnt(0)" ::: "memory"); \
  __builtin_amdgcn_sched_barrier(0); \
} while (0)

// ---- prep: im -> bf16 padded [48][256] ------------------------------------
__global__ void prep_im_kernel(const float* __restrict__ im,
                               u16* __restrict__ im_bf) {
  const int i = blockIdx.x;
  const int t = threadIdx.x;
  const float* src = im + (size_t)i * (RR * DD);
  u16* dst = im_bf + (size_t)i * (RP * DD);
  for (int e = t; e < RR * DD; e += 256) dst[e] = f2bf(src[e]);
  for (int e = RR * DD + t; e < RP * DD; e += 256) dst[e] = 0;
}

// ---- prep: Gram_i = im_i im_i^T via MFMA -> bf16 [48][64] -----------------
__global__ __launch_bounds__(64) void prep_gram_kernel(const u16* __restrict__ im_bf,
                                                       u16* __restrict__ gram_bf) {
  const int i = blockIdx.x;
  const int lane = threadIdx.x;
  const int lo = lane & 15, hi = lane >> 4;
  floatx4 acc[3][3];
  #pragma unroll
  for (int m = 0; m < 3; ++m)
    #pragma unroll
    for (int n = 0; n < 3; ++n) acc[m][n] = floatx4{0.f, 0.f, 0.f, 0.f};
  const u16* imp = im_bf + (size_t)i * (RP * DD);
  #pragma unroll 2
  for (int kt = 0; kt < 8; ++kt) {
    const int k0 = (kt << 5) + (hi << 3);
    bf16x8 f[3];
    #pragma unroll
    for (int m = 0; m < 3; ++m)
      f[m] = __builtin_bit_cast(bf16x8, *(const uint4*)(imp + (m * 16 + lo) * DD + k0));
    #pragma unroll
    for (int m = 0; m < 3; ++m)
      #pragma unroll
      for (int n = 0; n < 3; ++n)
        acc[m][n] = __builtin_amdgcn_mfma_f32_16x16x32_bf16(f[m], f[n], acc[m][n], 0, 0, 0);
  }
  u16* g = gram_bf + (size_t)i * (RP * KP);
  #pragma unroll
  for (int m = 0; m < 3; ++m)
    #pragma unroll
    for (int n = 0; n < 3; ++n)
      #pragma unroll
      for (int q = 0; q < 4; ++q)
        g[(m * 16 + hi * 4 + q) * KP + n * 16 + lo] = f2bf(acc[m][n][q]);
  // zero cols 48..63 (rows 36..47 are zero automatically via padded im rows)
  for (int e = lane; e < RP * 16; e += 64) {
    int r = e >> 4, c = e & 15;
    g[r * KP + 48 + c] = 0;
  }
}

// ---- prep: s -> bf16 padded [64][256], cn[j,l] = ||s_j[l]|| ---------------
__global__ void prep_s_kernel(const float* __restrict__ s,
                              u16* __restrict__ s_bf,
                              float* __restrict__ cn) {
  const int j = blockIdx.x;
  const int t = threadIdx.x;
  const float* src = s + (size_t)j * (LL * DD);
  u16* dst = s_bf + (size_t)j * (LP * DD);
  for (int e = t; e < LL * DD; e += 256) dst[e] = f2bf(src[e]);
  for (int e = LL * DD + t; e < LP * DD; e += 256) dst[e] = 0;
  const int l = t >> 2, q = t & 3;
  float acc = 0.f;
  if (l < LL) {
    const float* row = src + l * DD + q * 64;
    #pragma unroll 4
    for (int d = 0; d < 64; ++d) { float v = row[d]; acc = fmaf(v, v, acc); }
  }
  acc += __shfl_xor(acc, 1);
  acc += __shfl_xor(acc, 2);
  if (l < LL && q == 0) cn[j * LL + l] = sqrtf(acc);
}

// ---- main: 4 independent waves/block, one (i,j) pair per wave -------------
__global__ __launch_bounds__(256, 4) void xattn_kernel(
    const u16* __restrict__ im_bf, const u16* __restrict__ s_bf,
    const u16* __restrict__ gram_bf, const float* __restrict__ cn,
    const int* __restrict__ cap, float* __restrict__ scores) {
  __shared__ u16 buf[(4 * WROWS + SLOP) * ASTR];  // 29,104 B

  const int wid  = threadIdx.x >> 6;
  const int lane = threadIdx.x & 63;
  const int lo = lane & 15, hi = lane >> 4;
  const int i = blockIdx.x >> 6;
  const int j = ((blockIdx.x & 63) << 2) | wid;
  const int len = cap[j];
  const int nv = (len > 48) ? 4 : 3;  // wave-uniform n-tile count

  u16* mybuf = buf + wid * (WROWS * ASTR);

  // zero cols 48..63 of row `lane` (K-pad for matvec kt=1); rows 50..63 of
  // the last wave land in SLOP; reads of garbage rows only feed discarded
  // output columns (>= len).
  if (lane < WROWS) {
    uint2 z2 = {0u, 0u};
    uint2* zp = (uint2*)&mybuf[lane * ASTR + 48];
    zp[0] = z2; zp[1] = z2; zp[2] = z2; zp[3] = z2;
  }

  // ---- Phase A: G = im_i @ s_j^T (M=48, N=16*nv, K=256) -------------------
  floatx4 acc[3][4];
  #pragma unroll
  for (int m = 0; m < 3; ++m)
    #pragma unroll
    for (int n = 0; n < 4; ++n) acc[m][n] = floatx4{0.f, 0.f, 0.f, 0.f};

  const u16* imp = im_bf + (size_t)i * (RP * DD);
  const u16* sp  = s_bf  + (size_t)j * (LP * DD);

  #pragma unroll 2
  for (int kt = 0; kt < 8; ++kt) {
    const int k0 = (kt << 5) + (hi << 3);
    bf16x8 af[3], bfr[4];
    #pragma unroll
    for (int m = 0; m < 3; ++m)
      af[m] = __builtin_bit_cast(bf16x8, *(const uint4*)(imp + (m * 16 + lo) * DD + k0));
    #pragma unroll
    for (int n = 0; n < 4; ++n)
      if (n < nv)
        bfr[n] = __builtin_bit_cast(bf16x8, *(const uint4*)(sp + (n * 16 + lo) * DD + k0));
    #pragma unroll
    for (int m = 0; m < 3; ++m)
      #pragma unroll
      for (int n = 0; n < 4; ++n)
        if (n < nv)
          acc[m][n] = __builtin_amdgcn_mfma_f32_16x16x32_bf16(af[m], bfr[n], acc[m][n], 0, 0, 0);
  }

  // Gram A-fragments (issued early; consumed in matvec — latency hidden)
  bf16x8 gA[3][2];
  const u16* gp = gram_bf + (size_t)i * (RP * KP);
  #pragma unroll
  for (int m = 0; m < 3; ++m)
    #pragma unroll
    for (int kt = 0; kt < 2; ++kt)
      gA[m][kt] = __builtin_bit_cast(bf16x8,
          *(const uint4*)(gp + (m * 16 + lo) * KP + (kt << 5) + (hi << 3)));

  // ---- In-fragment row norms: ss[m][q] = sum_{valid cols} leaky(G)^2 ------
  // lane holds rows r=16m+4hi+q, cols c=16n+lo.
  float maskf[4];
  #pragma unroll
  for (int n = 0; n < 4; ++n) maskf[n] = (n * 16 + lo < len) ? 1.f : 0.f;

  float ss[3][4];
  #pragma unroll
  for (int m = 0; m < 3; ++m)
    #pragma unroll
    for (int q = 0; q < 4; ++q) ss[m][q] = 0.f;
  #pragma unroll
  for (int m = 0; m < 3; ++m)
    #pragma unroll
    for (int n = 0; n < 4; ++n)
      if (n < nv)
        #pragma unroll
        for (int q = 0; q < 4; ++q) {
          float g = acc[m][n][q];
          float v = fmaxf(g, 0.1f * g);
          ss[m][q] = fmaf(v * v, maskf[n], ss[m][q]);
        }
  #pragma unroll
  for (int off = 1; off < 16; off <<= 1)
    #pragma unroll
    for (int m = 0; m < 3; ++m)
      #pragma unroll
      for (int q = 0; q < 4; ++q)
        ss[m][q] += __shfl_xor(ss[m][q], off);

  float rinv[3][4];
  #pragma unroll
  for (int m = 0; m < 3; ++m)
    #pragma unroll
    for (int q = 0; q < 4; ++q)
      rinv[m][q] = 12.984255368000671f / (sqrtf(ss[m][q]) + 1e-8f); // 9*log2e/(||.||+eps)

  // ---- In-fragment softmax weights + num/psum partials; p -> LDS [l][r] ---
  const bool hiz = (hi == 0);   // rows 32+4hi+q are >= 36 iff hi >= 1 (m==2)
  float num[4], psum[4];
  #pragma unroll
  for (int n = 0; n < 4; ++n) { num[n] = 0.f; psum[n] = 0.f; }

  #pragma unroll
  for (int m = 0; m < 3; ++m) {
    #pragma unroll
    for (int n = 0; n < 4; ++n) {
      if (n < nv) {
        bf16x4 pb;
        #pragma unroll
        for (int q = 0; q < 4; ++q) {
          float g = acc[m][n][q];
          float v = fmaxf(g, 0.1f * g);
          float p = exp2f(v * rinv[m][q]);   // |arg|<=13 for valid cols
          if (m == 2) p = hiz ? p : 0.f;     // zero pad-rows 36..47
          psum[n] += p;
          num[n] = fmaf(p, g, num[n]);
          pb[q] = (__bf16)p;
        }
        // write p[rows 16m+4hi+0..3][col 16n+lo] to mybuf[col][row]
        if (n < 3 || lo < 2)                 // own rows only (l < 50)
          *(uint2*)&mybuf[(n * 16 + lo) * ASTR + m * 16 + hi * 4] =
              __builtin_bit_cast(uint2, pb);
      }
    }
  }
  // column sums: reduce over hi => every lane holds num/psum for col=16n+lo
  #pragma unroll
  for (int n = 0; n < 4; ++n) {
    num[n]  += __shfl_xor(num[n], 16);  num[n]  += __shfl_xor(num[n], 32);
    psum[n] += __shfl_xor(psum[n], 16); psum[n] += __shfl_xor(psum[n], 32);
  }
  WAVE_SYNC();

  // ---- matvec: t = Gram_i @ p  (M=48, N=16*nv, K=64 zero-padded) ----------
  floatx4 tac[3][4];
  #pragma unroll
  for (int m = 0; m < 3; ++m)
    #pragma unroll
    for (int n = 0; n < 4; ++n) tac[m][n] = floatx4{0.f, 0.f, 0.f, 0.f};

  #pragma unroll
  for (int kt = 0; kt < 2; ++kt) {
    bf16x8 gB[4];
    #pragma unroll
    for (int n = 0; n < 4; ++n) {
      if (n < nv) {
        const uint2* bp = (const uint2*)&mybuf[(n * 16 + lo) * ASTR + (kt << 5) + (hi << 3)];
        uint2 b0 = bp[0], b1 = bp[1];
        uint4 bb; bb.x = b0.x; bb.y = b0.y; bb.z = b1.x; bb.w = b1.y;
        gB[n] = __builtin_bit_cast(bf16x8, bb);
      }
    }
    #pragma unroll
    for (int m = 0; m < 3; ++m)
      #pragma unroll
      for (int n = 0; n < 4; ++n)
        if (n < nv)
          tac[m][n] = __builtin_amdgcn_mfma_f32_16x16x32_bf16(gA[m][kt], gB[n], tac[m][n], 0, 0, 0);
  }

  // ---- wn2 = sum_r p*t per column + finalize + max-free LSE ---------------
  float e4 = 0.f;
  #pragma unroll
  for (int n = 0; n < 4; ++n) {
    if (n < nv) {
      float w = 0.f;
      #pragma unroll
      for (int m = 0; m < 3; ++m) {
        uint2 av = *(const uint2*)&mybuf[(n * 16 + lo) * ASTR + m * 16 + hi * 4];
        w = fmaf(bflo(av.x), tac[m][n][0], w);
        w = fmaf(bfhi(av.x), tac[m][n][1], w);
        w = fmaf(bflo(av.y), tac[m][n][2], w);
        w = fmaf(bfhi(av.y), tac[m][n][3], w);
      }
      w += __shfl_xor(w, 16);
      w += __shfl_xor(w, 32);     // all hi-duplicates hold full sum over r
      const int col = n * 16 + lo;
      if (col < len) {
        float inv = __builtin_amdgcn_rcpf(psum[n]);
        float wn2 = fmaxf(w * inv * inv, 0.f);
        float nm  = num[n] * inv;
        float den = fmaxf(sqrtf(wn2) * cn[j * LL + col], 1e-8f);
        float sim = nm * __builtin_amdgcn_rcpf(den);
        e4 += exp2f(sim * 8.656170245333781f);   // 6*log2e; |arg| ~<= 9
      }
    }
  }
  #pragma unroll
  for (int off = 1; off < 64; off <<= 1) e4 += __shfl_xor(e4, off);
  if (lane == 0)
    scores[i * NN + j] = (log2f(e4) - 2.0f) * 0.11552453009332421f; // ln2/6
}

// ---- loss: hinge terms vs diagonal, full reduction ------------------------
__global__ void loss_kernel(const float* __restrict__ sc, float* __restrict__ out) {
  __shared__ float diag[NN];
  __shared__ float wsum[4];
  const int t = threadIdx.x;
  diag[t] = sc[t * NN + t];
  __syncthreads();
  const float di = diag[t];
  const float4* row = (const float4*)(sc + t * NN);
  float acc = 0.f;
  for (int q = 0; q < 64; ++q) {
    float4 v = row[q];
    const int b = q * 4;
    if (b + 0 != t) acc += fmaxf(0.2f + v.x - di, 0.f) + fmaxf(0.2f + v.x - diag[b + 0], 0.f);
    if (b + 1 != t) acc += fmaxf(0.2f + v.y - di, 0.f) + fmaxf(0.2f + v.y - diag[b + 1], 0.f);
    if (b + 2 != t) acc += fmaxf(0.2f + v.z - di, 0.f) + fmaxf(0.2f + v.z - diag[b + 2], 0.f);
    if (b + 3 != t) acc += fmaxf(0.2f + v.w - di, 0.f) + fmaxf(0.2f + v.w - diag[b + 3], 0.f);
  }
  #pragma unroll
  for (int o = 32; o; o >>= 1) acc += __shfl_xor(acc, o);
  if ((t & 63) == 0) wsum[t >> 6] = acc;
  __syncthreads();
  if (t == 0) out[0] = wsum[0] + wsum[1] + wsum[2] + wsum[3];
}

// ---------------------------------------------------------------------------
extern "C" void kernel_launch(void* const* d_in, const int* in_sizes, int n_in,
                              void* d_out, int out_size, void* d_ws, size_t ws_size,
                              hipStream_t stream) {
  const float* im = (const float*)d_in[0];
  const float* s  = (const float*)d_in[1];
  const int* cap  = (const int*)d_in[2];
  float* out = (float*)d_out;

  char* ws = (char*)d_ws;
  u16*   im_bf   = (u16*)(ws);                         //  6,291,456 B
  u16*   s_bf    = (u16*)(ws + 6291456);               //  8,388,608 B
  u16*   gram_bf = (u16*)(ws + 14680064);              //  1,572,864 B
  float* cn      = (float*)(ws + 16252928);            //     51,200 B
  float* scores  = (float*)(ws + 16304128);            //    262,144 B

  prep_im_kernel<<<dim3(NN), dim3(256), 0, stream>>>(im, im_bf);
  prep_s_kernel<<<dim3(NN), dim3(256), 0, stream>>>(s, s_bf, cn);
  prep_gram_kernel<<<dim3(NN), dim3(64), 0, stream>>>(im_bf, gram_bf);
  xattn_kernel<<<dim3(NN * 64), dim3(256), 0, stream>>>(im_bf, s_bf, gram_bf, cn, cap, scores);
  loss_kernel<<<dim3(1), dim3(256), 0, stream>>>(scores, out);
}

// Round 6
// 522.763 us; speedup vs baseline: 1.3740x; 1.0805x over previous
//
#include <hip/hip_runtime.h>

// ---------------------------------------------------------------------------
// ContrastiveLoss (SCAN t2i cross-attention) on MI355X — round 6.
// N=256x256 pairs, R=36 regions, L=50 words, D=256.
// Barrier-free xattn; softmax/norms computed IN the MFMA fragments.
// r6 change vs r5: Gram A-fragments loaded LATE (after softmax) — cuts peak
// register liveness below the 128-reg cap => no scratch spill.
// ---------------------------------------------------------------------------

typedef unsigned short u16;
typedef unsigned int u32;

typedef __attribute__((ext_vector_type(8))) __bf16 bf16x8;
typedef __attribute__((ext_vector_type(4))) __bf16 bf16x4;
typedef __attribute__((ext_vector_type(4))) float floatx4;

#define NN 256
#define RR 36
#define LL 50
#define DD 256
#define RP 48    // padded region dim
#define LP 64    // padded word dim (s rows)
#define KP 64    // gram row stride / matvec K
#define ASTR 68  // u16 stride of LDS rows (136B: lo-lanes spread all banks)
#define WROWS 50 // logical LDS rows per wave
#define SLOP 14  // shared overflow rows (reads of rows 50..63 land here)

__device__ __forceinline__ u16 f2bf(float v) {
  u32 u = __builtin_bit_cast(u32, v);
  u += 0x7fffu + ((u >> 16) & 1u);   // RNE (inputs never NaN)
  return (u16)(u >> 16);
}
__device__ __forceinline__ float bflo(u32 w) { return __builtin_bit_cast(float, w << 16); }
__device__ __forceinline__ float bfhi(u32 w) { return __builtin_bit_cast(float, w & 0xffff0000u); }

#define WAVE_SYNC() do { \
  asm volatile("s_waitcnt lgkmcnt(0)" ::: "memory"); \
  __builtin_amdgcn_sched_barrier(0); \
} while (0)

// ---- prep: im -> bf16 padded [48][256] ------------------------------------
__global__ void prep_im_kernel(const float* __restrict__ im,
                               u16* __restrict__ im_bf) {
  const int i = blockIdx.x;
  const int t = threadIdx.x;
  const float* src = im + (size_t)i * (RR * DD);
  u16* dst = im_bf + (size_t)i * (RP * DD);
  for (int e = t; e < RR * DD; e += 256) dst[e] = f2bf(src[e]);
  for (int e = RR * DD + t; e < RP * DD; e += 256) dst[e] = 0;
}

// ---- prep: Gram_i = im_i im_i^T via MFMA -> bf16 [48][64] -----------------
__global__ __launch_bounds__(64) void prep_gram_kernel(const u16* __restrict__ im_bf,
                                                       u16* __restrict__ gram_bf) {
  const int i = blockIdx.x;
  const int lane = threadIdx.x;
  const int lo = lane & 15, hi = lane >> 4;
  floatx4 acc[3][3];
  #pragma unroll
  for (int m = 0; m < 3; ++m)
    #pragma unroll
    for (int n = 0; n < 3; ++n) acc[m][n] = floatx4{0.f, 0.f, 0.f, 0.f};
  const u16* imp = im_bf + (size_t)i * (RP * DD);
  #pragma unroll 2
  for (int kt = 0; kt < 8; ++kt) {
    const int k0 = (kt << 5) + (hi << 3);
    bf16x8 f[3];
    #pragma unroll
    for (int m = 0; m < 3; ++m)
      f[m] = __builtin_bit_cast(bf16x8, *(const uint4*)(imp + (m * 16 + lo) * DD + k0));
    #pragma unroll
    for (int m = 0; m < 3; ++m)
      #pragma unroll
      for (int n = 0; n < 3; ++n)
        acc[m][n] = __builtin_amdgcn_mfma_f32_16x16x32_bf16(f[m], f[n], acc[m][n], 0, 0, 0);
  }
  u16* g = gram_bf + (size_t)i * (RP * KP);
  #pragma unroll
  for (int m = 0; m < 3; ++m)
    #pragma unroll
    for (int n = 0; n < 3; ++n)
      #pragma unroll
      for (int q = 0; q < 4; ++q)
        g[(m * 16 + hi * 4 + q) * KP + n * 16 + lo] = f2bf(acc[m][n][q]);
  // zero cols 48..63 (rows 36..47 are zero automatically via padded im rows)
  for (int e = lane; e < RP * 16; e += 64) {
    int r = e >> 4, c = e & 15;
    g[r * KP + 48 + c] = 0;
  }
}

// ---- prep: s -> bf16 padded [64][256], cn[j,l] = ||s_j[l]|| ---------------
__global__ void prep_s_kernel(const float* __restrict__ s,
                              u16* __restrict__ s_bf,
                              float* __restrict__ cn) {
  const int j = blockIdx.x;
  const int t = threadIdx.x;
  const float* src = s + (size_t)j * (LL * DD);
  u16* dst = s_bf + (size_t)j * (LP * DD);
  for (int e = t; e < LL * DD; e += 256) dst[e] = f2bf(src[e]);
  for (int e = LL * DD + t; e < LP * DD; e += 256) dst[e] = 0;
  const int l = t >> 2, q = t & 3;
  float acc = 0.f;
  if (l < LL) {
    const float* row = src + l * DD + q * 64;
    #pragma unroll 4
    for (int d = 0; d < 64; ++d) { float v = row[d]; acc = fmaf(v, v, acc); }
  }
  acc += __shfl_xor(acc, 1);
  acc += __shfl_xor(acc, 2);
  if (l < LL && q == 0) cn[j * LL + l] = sqrtf(acc);
}

// ---- main: 4 independent waves/block, one (i,j) pair per wave -------------
__global__ __launch_bounds__(256, 4) void xattn_kernel(
    const u16* __restrict__ im_bf, const u16* __restrict__ s_bf,
    const u16* __restrict__ gram_bf, const float* __restrict__ cn,
    const int* __restrict__ cap, float* __restrict__ scores) {
  __shared__ u16 buf[(4 * WROWS + SLOP) * ASTR];  // 29,104 B

  const int wid  = threadIdx.x >> 6;
  const int lane = threadIdx.x & 63;
  const int lo = lane & 15, hi = lane >> 4;
  const int i = blockIdx.x >> 6;
  const int j = ((blockIdx.x & 63) << 2) | wid;
  const int len = cap[j];
  const int nv = (len > 48) ? 4 : 3;  // wave-uniform n-tile count

  u16* mybuf = buf + wid * (WROWS * ASTR);

  // zero cols 48..63 of row `lane` (K-pad for matvec kt=1); rows 50..63 of
  // the last wave land in SLOP; reads of garbage rows only feed discarded
  // output columns (>= len).
  if (lane < WROWS) {
    uint2 z2 = {0u, 0u};
    uint2* zp = (uint2*)&mybuf[lane * ASTR + 48];
    zp[0] = z2; zp[1] = z2; zp[2] = z2; zp[3] = z2;
  }

  // ---- Phase A: G = im_i @ s_j^T (M=48, N=16*nv, K=256) -------------------
  floatx4 acc[3][4];
  #pragma unroll
  for (int m = 0; m < 3; ++m)
    #pragma unroll
    for (int n = 0; n < 4; ++n) acc[m][n] = floatx4{0.f, 0.f, 0.f, 0.f};

  const u16* imp = im_bf + (size_t)i * (RP * DD);
  const u16* sp  = s_bf  + (size_t)j * (LP * DD);

  #pragma unroll 2
  for (int kt = 0; kt < 8; ++kt) {
    const int k0 = (kt << 5) + (hi << 3);
    bf16x8 af[3], bfr[4];
    #pragma unroll
    for (int m = 0; m < 3; ++m)
      af[m] = __builtin_bit_cast(bf16x8, *(const uint4*)(imp + (m * 16 + lo) * DD + k0));
    #pragma unroll
    for (int n = 0; n < 4; ++n)
      if (n < nv)
        bfr[n] = __builtin_bit_cast(bf16x8, *(const uint4*)(sp + (n * 16 + lo) * DD + k0));
    #pragma unroll
    for (int m = 0; m < 3; ++m)
      #pragma unroll
      for (int n = 0; n < 4; ++n)
        if (n < nv)
          acc[m][n] = __builtin_amdgcn_mfma_f32_16x16x32_bf16(af[m], bfr[n], acc[m][n], 0, 0, 0);
  }

  // ---- In-fragment row norms: ss[m][q] = sum_{valid cols} leaky(G)^2 ------
  // lane holds rows r=16m+4hi+q, cols c=16n+lo.
  float maskf[4];
  #pragma unroll
  for (int n = 0; n < 4; ++n) maskf[n] = (n * 16 + lo < len) ? 1.f : 0.f;

  float ss[3][4];
  #pragma unroll
  for (int m = 0; m < 3; ++m)
    #pragma unroll
    for (int q = 0; q < 4; ++q) ss[m][q] = 0.f;
  #pragma unroll
  for (int m = 0; m < 3; ++m)
    #pragma unroll
    for (int n = 0; n < 4; ++n)
      if (n < nv)
        #pragma unroll
        for (int q = 0; q < 4; ++q) {
          float g = acc[m][n][q];
          float v = fmaxf(g, 0.1f * g);
          ss[m][q] = fmaf(v * v, maskf[n], ss[m][q]);
        }
  #pragma unroll
  for (int off = 1; off < 16; off <<= 1)
    #pragma unroll
    for (int m = 0; m < 3; ++m)
      #pragma unroll
      for (int q = 0; q < 4; ++q)
        ss[m][q] += __shfl_xor(ss[m][q], off);

  float rinv[3][4];
  #pragma unroll
  for (int m = 0; m < 3; ++m)
    #pragma unroll
    for (int q = 0; q < 4; ++q)
      rinv[m][q] = 12.984255368000671f / (sqrtf(ss[m][q]) + 1e-8f); // 9*log2e/(||.||+eps)

  // ---- In-fragment softmax weights + num/psum partials; p -> LDS [l][r] ---
  const bool hiz = (hi == 0);   // rows 32+4hi+q are >= 36 iff hi >= 1 (m==2)
  float num[4], psum[4];
  #pragma unroll
  for (int n = 0; n < 4; ++n) { num[n] = 0.f; psum[n] = 0.f; }

  #pragma unroll
  for (int m = 0; m < 3; ++m) {
    #pragma unroll
    for (int n = 0; n < 4; ++n) {
      if (n < nv) {
        bf16x4 pb;
        #pragma unroll
        for (int q = 0; q < 4; ++q) {
          float g = acc[m][n][q];
          float v = fmaxf(g, 0.1f * g);
          float p = exp2f(v * rinv[m][q]);   // |arg|<=13 for valid cols
          if (m == 2) p = hiz ? p : 0.f;     // zero pad-rows 36..47
          psum[n] += p;
          num[n] = fmaf(p, g, num[n]);
          pb[q] = (__bf16)p;
        }
        // write p[rows 16m+4hi+0..3][col 16n+lo] to mybuf[col][row]
        if (n < 3 || lo < 2)                 // own rows only (l < 50)
          *(uint2*)&mybuf[(n * 16 + lo) * ASTR + m * 16 + hi * 4] =
              __builtin_bit_cast(uint2, pb);
      }
    }
  }
  // column sums: reduce over hi => every lane holds num/psum for col=16n+lo
  #pragma unroll
  for (int n = 0; n < 4; ++n) {
    num[n]  += __shfl_xor(num[n], 16);  num[n]  += __shfl_xor(num[n], 32);
    psum[n] += __shfl_xor(psum[n], 16); psum[n] += __shfl_xor(psum[n], 32);
  }
  WAVE_SYNC();

  // ---- Gram A-fragments: loaded LATE (acc now dead) — no spill ------------
  bf16x8 gA[3][2];
  const u16* gp = gram_bf + (size_t)i * (RP * KP);
  #pragma unroll
  for (int m = 0; m < 3; ++m)
    #pragma unroll
    for (int kt = 0; kt < 2; ++kt)
      gA[m][kt] = __builtin_bit_cast(bf16x8,
          *(const uint4*)(gp + (m * 16 + lo) * KP + (kt << 5) + (hi << 3)));

  // ---- matvec: t = Gram_i @ p  (M=48, N=16*nv, K=64 zero-padded) ----------
  floatx4 tac[3][4];
  #pragma unroll
  for (int m = 0; m < 3; ++m)
    #pragma unroll
    for (int n = 0; n < 4; ++n) tac[m][n] = floatx4{0.f, 0.f, 0.f, 0.f};

  #pragma unroll
  for (int kt = 0; kt < 2; ++kt) {
    bf16x8 gB[4];
    #pragma unroll
    for (int n = 0; n < 4; ++n) {
      if (n < nv) {
        const uint2* bp = (const uint2*)&mybuf[(n * 16 + lo) * ASTR + (kt << 5) + (hi << 3)];
        uint2 b0 = bp[0], b1 = bp[1];
        uint4 bb; bb.x = b0.x; bb.y = b0.y; bb.z = b1.x; bb.w = b1.y;
        gB[n] = __builtin_bit_cast(bf16x8, bb);
      }
    }
    #pragma unroll
    for (int m = 0; m < 3; ++m)
      #pragma unroll
      for (int n = 0; n < 4; ++n)
        if (n < nv)
          tac[m][n] = __builtin_amdgcn_mfma_f32_16x16x32_bf16(gA[m][kt], gB[n], tac[m][n], 0, 0, 0);
  }

  // ---- wn2 = sum_r p*t per column + finalize + max-free LSE ---------------
  float e4 = 0.f;
  #pragma unroll
  for (int n = 0; n < 4; ++n) {
    if (n < nv) {
      float w = 0.f;
      #pragma unroll
      for (int m = 0; m < 3; ++m) {
        uint2 av = *(const uint2*)&mybuf[(n * 16 + lo) * ASTR + m * 16 + hi * 4];
        w = fmaf(bflo(av.x), tac[m][n][0], w);
        w = fmaf(bfhi(av.x), tac[m][n][1], w);
        w = fmaf(bflo(av.y), tac[m][n][2], w);
        w = fmaf(bfhi(av.y), tac[m][n][3], w);
      }
      w += __shfl_xor(w, 16);
      w += __shfl_xor(w, 32);     // all hi-duplicates hold full sum over r
      const int col = n * 16 + lo;
      if (col < len) {
        float inv = __builtin_amdgcn_rcpf(psum[n]);
        float wn2 = fmaxf(w * inv * inv, 0.f);
        float nm  = num[n] * inv;
        float den = fmaxf(sqrtf(wn2) * cn[j * LL + col], 1e-8f);
        float sim = nm * __builtin_amdgcn_rcpf(den);
        e4 += exp2f(sim * 8.656170245333781f);   // 6*log2e; |arg| ~<= 9
      }
    }
  }
  #pragma unroll
  for (int off = 1; off < 64; off <<= 1) e4 += __shfl_xor(e4, off);
  if (lane == 0)
    scores[i * NN + j] = (log2f(e4) - 2.0f) * 0.11552453009332421f; // ln2/6
}

// ---- loss: hinge terms vs diagonal, full reduction ------------------------
__global__ void loss_kernel(const float* __restrict__ sc, float* __restrict__ out) {
  __shared__ float diag[NN];
  __shared__ float wsum[4];
  const int t = threadIdx.x;
  diag[t] = sc[t * NN + t];
  __syncthreads();
  const float di = diag[t];
  const float4* row = (const float4*)(sc + t * NN);
  float acc = 0.f;
  for (int q = 0; q < 64; ++q) {
    float4 v = row[q];
    const int b = q * 4;
    if (b + 0 != t) acc += fmaxf(0.2f + v.x - di, 0.f) + fmaxf(0.2f + v.x - diag[b + 0], 0.f);
    if (b + 1 != t) acc += fmaxf(0.2f + v.y - di, 0.f) + fmaxf(0.2f + v.y - diag[b + 1], 0.f);
    if (b + 2 != t) acc += fmaxf(0.2f + v.z - di, 0.f) + fmaxf(0.2f + v.z - diag[b + 2], 0.f);
    if (b + 3 != t) acc += fmaxf(0.2f + v.w - di, 0.f) + fmaxf(0.2f + v.w - diag[b + 3], 0.f);
  }
  #pragma unroll
  for (int o = 32; o; o >>= 1) acc += __shfl_xor(acc, o);
  if ((t & 63) == 0) wsum[t >> 6] = acc;
  __syncthreads();
  if (t == 0) out[0] = wsum[0] + wsum[1] + wsum[2] + wsum[3];
}

// ---------------------------------------------------------------------------
extern "C" void kernel_launch(void* const* d_in, const int* in_sizes, int n_in,
                              void* d_out, int out_size, void* d_ws, size_t ws_size,
                              hipStream_t stream) {
  const float* im = (const float*)d_in[0];
  const float* s  = (const float*)d_in[1];
  const int* cap  = (const int*)d_in[2];
  float* out = (float*)d_out;

  char* ws = (char*)d_ws;
  u16*   im_bf   = (u16*)(ws);                         //  6,291,456 B
  u16*   s_bf    = (u16*)(ws + 6291456);               //  8,388,608 B
  u16*   gram_bf = (u16*)(ws + 14680064);              //  1,572,864 B
  float* cn      = (float*)(ws + 16252928);            //     51,200 B
  float* scores  = (float*)(ws + 16304128);            //    262,144 B

  prep_im_kernel<<<dim3(NN), dim3(256), 0, stream>>>(im, im_bf);
  prep_s_kernel<<<dim3(NN), dim3(256), 0, stream>>>(s, s_bf, cn);
  prep_gram_kernel<<<dim3(NN), dim3(64), 0, stream>>>(im_bf, gram_bf);
  xattn_kernel<<<dim3(NN * 64), dim3(256), 0, stream>>>(im_bf, s_bf, gram_bf, cn, cap, scores);
  loss_kernel<<<dim3(1), dim3(256), 0, stream>>>(scores, out);
}